// Round 6
// baseline (135.555 us; speedup 1.0000x reference)
//
#include <hip/hip_runtime.h>

#define RES 1024
#define NROOMS 8
#define NBUCKETS 256                 // 4 grid rows per bucket
#define BINS_PER_BUCKET (4 * RES)    // 4096 bins
#define CAP 32768                    // entries per bucket (mean ~19531, sigma ~140)
#define SWPB 8                       // waves per scatter block (512 threads)
#define AGB 8192                     // agents per block (512 thr * 16 agents)

typedef float  f32x4 __attribute__((ext_vector_type(4)));
typedef unsigned int u32x4 __attribute__((ext_vector_type(4)));

// ---------------------------------------------------------------------------
// Pass 1: partition agents into per-bucket segments of 2-byte bin codes.
// Packed per-agent state: (bucket<<24)|(elem<<12)|rank in ONE uint (rank<1024,
// elem<4096), validity in a 16-bit mask. __launch_bounds__(512,6): 24
// waves/CU, no spill.
// ---------------------------------------------------------------------------
__global__ __launch_bounds__(512, 6) void scatter_kernel(
    const f32x4* __restrict__ pos, int n4, int nagents,
    unsigned short* __restrict__ buf, unsigned int* __restrict__ cursor)
{
    __shared__ unsigned int   cnt[SWPB][NBUCKETS];   // per-wave counts (rank src)
    __shared__ unsigned int   sbase[SWPB][NBUCKETS]; // staged base per (wave,bucket)
    __shared__ unsigned int   pstart[NBUCKETS];      // staged start per bucket
    __shared__ unsigned int   ptotal[NBUCKETS];      // block total per bucket
    __shared__ unsigned int   gbase[NBUCKETS];       // global base per bucket
    __shared__ unsigned int   wsum[4];
    __shared__ unsigned short staged[AGB];           // 16 KB

    int tid  = threadIdx.x;
    int wv   = tid >> 6;
    int lane = tid & 63;

    #pragma unroll
    for (int i = 0; i < (SWPB * NBUCKETS) / 512; ++i)
        ((unsigned int*)cnt)[tid + 512 * i] = 0u;
    __syncthreads();

    // Phase A: load agents, compute codes, count+rank in one LDS atomic.
    unsigned int pk[16];
    unsigned int valid = 0u;
    int base4 = blockIdx.x * (AGB / 2);              // 4096 float4 per block
    #pragma unroll
    for (int k = 0; k < 8; ++k) {
        int i4 = base4 + (k << 9) + tid;
        if (i4 < n4) {
            f32x4 p = __builtin_nontemporal_load(&pos[i4]);
            int ix0 = min(max((int)(p.x * 1024.0f), 0), 1023);
            int iy0 = min(max((int)(p.y * 1024.0f), 0), 1023);
            int ix1 = min(max((int)(p.z * 1024.0f), 0), 1023);
            int iy1 = min(max((int)(p.w * 1024.0f), 0), 1023);
            unsigned int b0 = (unsigned int)(ix0 >> 2);
            unsigned int b1 = (unsigned int)(ix1 >> 2);
            unsigned int e0 = (unsigned int)(((ix0 & 3) << 10) | iy0);
            unsigned int e1 = (unsigned int)(((ix1 & 3) << 10) | iy1);
            unsigned int r0 = atomicAdd(&cnt[wv][b0], 1u);
            unsigned int r1 = atomicAdd(&cnt[wv][b1], 1u);
            pk[2 * k]     = (b0 << 24) | (e0 << 12) | (r0 & 0xFFFu);
            pk[2 * k + 1] = (b1 << 24) | (e1 << 12) | (r1 & 0xFFFu);
            valid |= 3u << (2 * k);
        }
    }
    __syncthreads();

    // Phase B: per-bucket totals, cross-wave bases, block prefix, reservation.
    if (tid < NBUCKETS) {
        unsigned int run = 0;
        #pragma unroll
        for (int w = 0; w < SWPB; ++w) {
            unsigned int c = cnt[w][tid];
            sbase[w][tid] = run;                     // wave-exclusive base
            run += c;
        }
        ptotal[tid] = run;
        gbase[tid]  = run ? atomicAdd(&cursor[tid], run) : 0u;
        unsigned int t = run;                        // inclusive scan within wave
        #pragma unroll
        for (int off = 1; off < 64; off <<= 1) {
            unsigned int v = (unsigned int)__shfl_up((int)t, off, 64);
            if (lane >= off) t += v;
        }
        if (lane == 63) wsum[wv] = t;
        pstart[tid] = t - run;                       // wave-local exclusive
    }
    __syncthreads();
    if (tid < NBUCKETS) {
        unsigned int off = 0;
        #pragma unroll
        for (int w = 0; w < 3; ++w) if (w < wv) off += wsum[w];
        unsigned int ps = pstart[tid] + off;         // block-local exclusive prefix
        pstart[tid] = ps;
        #pragma unroll
        for (int w = 0; w < SWPB; ++w) sbase[w][tid] += ps;
    }
    __syncthreads();

    // Phase C: scatter codes into LDS staging ordered by bucket.
    #pragma unroll
    for (int k = 0; k < 16; ++k) {
        if (valid & (1u << k)) {
            unsigned int cd = pk[k];
            unsigned int b = cd >> 24;
            staged[sbase[wv][b] + (cd & 0xFFFu)] =
                (unsigned short)((cd >> 12) & 0xFFFu);
        }
    }
    __syncthreads();

    // Phase D: coalesced copy-out; wave w owns buckets [32w, 32w+32).
    // Pair-packed uint stores with head/tail fixup for alignment.
    for (int bb = 0; bb < 32; ++bb) {
        int b = (wv << 5) + bb;
        unsigned int n = ptotal[b];
        if (n == 0) continue;
        unsigned int ps = pstart[b];
        unsigned int gb = gbase[b];
        unsigned int head = gb & 1u;                 // 1 -> first elem solo
        if (head && lane == 0) {
            if (gb < CAP) buf[b * CAP + gb] = staged[ps];
        }
        unsigned int body  = n - head;
        unsigned int npair = body >> 1;
        for (unsigned int q = lane; q < npair; q += 64) {
            unsigned int e  = head + 2 * q;
            unsigned int lo = staged[ps + e];
            unsigned int hi = staged[ps + e + 1];
            unsigned int p  = gb + e;                // even
            if (p + 1 < CAP)
                *(unsigned int*)(buf + (size_t)b * CAP + p) = lo | (hi << 16);
            else if (p < CAP)
                buf[(size_t)b * CAP + p] = (unsigned short)lo;
        }
        if ((body & 1u) && lane == 0) {
            unsigned int e = head + 2 * npair;
            unsigned int p = gb + e;
            if (p < CAP) buf[(size_t)b * CAP + p] = staged[ps + e];
        }
    }

    // odd-count tail agent
    if (blockIdx.x == 0 && tid == 0 && (nagents & 1)) {
        const float* t = (const float*)pos;
        float px = t[2 * (nagents - 1)];
        float py = t[2 * (nagents - 1) + 1];
        int ix = min(max((int)(px * 1024.0f), 0), 1023);
        int iy = min(max((int)(py * 1024.0f), 0), 1023);
        unsigned int b = (unsigned int)(ix >> 2);
        unsigned int p = atomicAdd(&cursor[b], 1u);
        if (p < CAP) buf[b * CAP + p] = (unsigned short)(((ix & 3) << 10) | iy);
    }
}

// ---------------------------------------------------------------------------
// Pass 2: one block per bucket — LDS histogram from paired-code reads,
// uint4 stores, fused block-max + one atomicMax. No pre-zero of counts.
// ---------------------------------------------------------------------------
__global__ __launch_bounds__(1024) void hist_build_kernel(
    const unsigned short* __restrict__ buf,
    const unsigned int* __restrict__ cursor,
    unsigned int* __restrict__ counts,
    unsigned int* __restrict__ out_max)
{
    __shared__ __align__(16) unsigned int h[BINS_PER_BUCKET];   // 16 KB
    int b = blockIdx.x, tid = threadIdx.x;
    #pragma unroll
    for (int i = 0; i < BINS_PER_BUCKET / 1024; ++i) h[tid + 1024 * i] = 0u;
    __syncthreads();

    unsigned int n = min(cursor[b], (unsigned int)CAP);
    const unsigned short* seg = buf + (size_t)b * CAP;
    unsigned int n2 = n & ~1u;
    for (unsigned int i = 2 * tid; i < n2; i += 2048) {
        unsigned int u = *(const unsigned int*)(seg + i);   // seg 4B-aligned, i even
        atomicAdd(&h[u & 0xFFFFu], 1u);
        atomicAdd(&h[u >> 16], 1u);
    }
    if (tid == 0 && (n & 1)) atomicAdd(&h[seg[n - 1]], 1u);
    __syncthreads();

    u32x4 v = ((const u32x4*)h)[tid];
    ((u32x4*)counts)[(size_t)b * (BINS_PER_BUCKET / 4) + tid] = v;
    unsigned int m = max(max(v.x, v.y), max(v.z, v.w));
    #pragma unroll
    for (int off = 32; off > 0; off >>= 1)
        m = max(m, (unsigned int)__shfl_down((int)m, off, 64));
    __shared__ unsigned int sm[16];
    if ((tid & 63) == 0) sm[tid >> 6] = m;
    __syncthreads();
    if (tid == 0) {
        #pragma unroll
        for (int w = 1; w < 16; ++w) m = max(m, sm[w]);
        atomicMax(out_max, m);
    }
}

// ---------------------------------------------------------------------------
// Fallback (direct global atomics) if ws_size is too small.
// ---------------------------------------------------------------------------
__global__ __launch_bounds__(256) void hist_atomic_kernel(
    const float4* __restrict__ pos, int n4, int nagents,
    unsigned int* __restrict__ counts)
{
    int idx = blockIdx.x * blockDim.x + threadIdx.x;
    int stride = gridDim.x * blockDim.x;
    for (int i = idx; i < n4; i += stride) {
        float4 p = pos[i];
        int ix0 = min(max((int)(p.x * 1024.0f), 0), 1023);
        int iy0 = min(max((int)(p.y * 1024.0f), 0), 1023);
        int ix1 = min(max((int)(p.z * 1024.0f), 0), 1023);
        int iy1 = min(max((int)(p.w * 1024.0f), 0), 1023);
        atomicAdd(&counts[(ix0 << 10) + iy0], 1u);
        atomicAdd(&counts[(ix1 << 10) + iy1], 1u);
    }
    if (idx == 0 && (nagents & 1)) {
        const float* t = (const float*)pos;
        int ix = min(max((int)(t[2 * (nagents - 1)] * 1024.0f), 0), 1023);
        int iy = min(max((int)(t[2 * (nagents - 1) + 1] * 1024.0f), 0), 1023);
        atomicAdd(&counts[(ix << 10) + iy], 1u);
    }
}

__global__ __launch_bounds__(256) void max_kernel(
    const uint4* __restrict__ counts, unsigned int* __restrict__ out_max)
{
    int idx = blockIdx.x * blockDim.x + threadIdx.x;
    int stride = gridDim.x * blockDim.x;
    unsigned int m = 0;
    const int n4 = (RES * RES) / 4;
    for (int i = idx; i < n4; i += stride) {
        uint4 c = counts[i];
        m = max(m, max(max(c.x, c.y), max(c.z, c.w)));
    }
    #pragma unroll
    for (int off = 32; off > 0; off >>= 1)
        m = max(m, (unsigned int)__shfl_down((int)m, off, 64));
    __shared__ unsigned int sm[4];
    if ((threadIdx.x & 63) == 0) sm[threadIdx.x >> 6] = m;
    __syncthreads();
    if (threadIdx.x == 0) {
        m = max(max(sm[0], sm[1]), max(sm[2], sm[3]));
        atomicMax(out_max, m);
    }
}

// ---------------------------------------------------------------------------
// Pass 3: dynamic_layout for 8 rooms + in-place flow normalization.
// Nontemporal streaming via ext_vector_type (builtin rejects HIP float4).
// ---------------------------------------------------------------------------
__global__ __launch_bounds__(256) void final_kernel(
    const float* __restrict__ room_params,
    const f32x4* __restrict__ wall,
    f32x4* __restrict__ dyn,
    float* __restrict__ flow,
    const unsigned int* __restrict__ maxp)
{
    int idx = blockIdx.x * blockDim.x + threadIdx.x;   // 0 .. 262143
    int i  = idx >> 8;
    int j0 = (idx & 255) << 2;

    const float inv1023 = 1.0f / 1023.0f;
    float x  = (float)i * inv1023;
    float y0 = (float)(j0 + 0) * inv1023;
    float y1 = (float)(j0 + 1) * inv1023;
    float y2 = (float)(j0 + 2) * inv1023;
    float y3 = (float)(j0 + 3) * inv1023;

    f32x4 w = __builtin_nontemporal_load(&wall[idx]);
    float omx = 1.0f - w.x;
    float omy = 1.0f - w.y;
    float omz = 1.0f - w.z;
    float omw = 1.0f - w.w;

    u32x4 c = __builtin_nontemporal_load(&((const u32x4*)flow)[idx]);
    float inv = 1.0f / ((float)(*maxp) + 1e-6f);
    f32x4 f;
    f.x = (float)c.x * inv;
    f.y = (float)c.y * inv;
    f.z = (float)c.z * inv;
    f.w = (float)c.w * inv;
    __builtin_nontemporal_store(f, &((f32x4*)flow)[idx]);

    const int plane4 = (RES * RES) / 4;
    #pragma unroll
    for (int r = 0; r < NROOMS; ++r) {
        float cx = room_params[4 * r + 0];
        float cy = room_params[4 * r + 1];
        float sx = room_params[4 * r + 2];
        float sy = room_params[4 * r + 3];
        float isx = 1.0f / (2.0f * sx * sx);
        float isy = 1.0f / (2.0f * sy * sy);
        float dx = x - cx;
        float ax = dx * dx * isx;
        float d0 = y0 - cy, d1 = y1 - cy, d2 = y2 - cy, d3 = y3 - cy;
        f32x4 d;
        d.x = __expf(-(ax + d0 * d0 * isy)) * omx;
        d.y = __expf(-(ax + d1 * d1 * isy)) * omy;
        d.z = __expf(-(ax + d2 * d2 * isy)) * omz;
        d.w = __expf(-(ax + d3 * d3 * isy)) * omw;
        __builtin_nontemporal_store(d, &dyn[(size_t)r * plane4 + idx]);
    }
}

extern "C" void kernel_launch(void* const* d_in, const int* in_sizes, int n_in,
                              void* d_out, int out_size, void* d_ws, size_t ws_size,
                              hipStream_t stream) {
    const float* agents      = (const float*)d_in[0];  // (N,2)
    const float* room_params = (const float*)d_in[1];  // (8,4)
    const float* wall        = (const float*)d_in[2];  // (1024,1024)

    float* dyn  = (float*)d_out;
    float* flow = (float*)d_out + (size_t)NROOMS * RES * RES;
    unsigned int* counts = (unsigned int*)flow;

    int nagents = in_sizes[0] / 2;
    int n4 = nagents / 2;

    // ws layout: [0,1024) cursors, [1024,1028) max, [2048, 2048+16MB) buf
    size_t need = 2048 + (size_t)NBUCKETS * CAP * sizeof(unsigned short);

    if (ws_size >= need) {
        unsigned int*   cursor = (unsigned int*)d_ws;
        unsigned int*   maxp   = (unsigned int*)((char*)d_ws + 1024);
        unsigned short* buf    = (unsigned short*)((char*)d_ws + 2048);

        (void)hipMemsetAsync(d_ws, 0, 2048, stream);           // cursors + max
        int nblk = (n4 + (AGB / 2) - 1) / (AGB / 2);           // 4096 float4/block
        scatter_kernel<<<nblk, 512, 0, stream>>>((const f32x4*)agents, n4, nagents,
                                                 buf, cursor);
        hist_build_kernel<<<NBUCKETS, 1024, 0, stream>>>(buf, cursor, counts, maxp);
        final_kernel<<<(RES * RES / 4) / 256, 256, 0, stream>>>(
            room_params, (const f32x4*)wall, (f32x4*)dyn, flow, maxp);
    } else {
        unsigned int* maxp = (unsigned int*)d_ws;
        (void)hipMemsetAsync(flow, 0, (size_t)RES * RES * sizeof(float), stream);
        (void)hipMemsetAsync(maxp, 0, sizeof(unsigned int), stream);
        hist_atomic_kernel<<<1280, 256, 0, stream>>>((const float4*)agents, n4, nagents, counts);
        max_kernel<<<256, 256, 0, stream>>>((const uint4*)counts, maxp);
        final_kernel<<<(RES * RES / 4) / 256, 256, 0, stream>>>(
            room_params, (const f32x4*)wall, (f32x4*)dyn, flow, maxp);
    }
}

// Round 7
// 129.652 us; speedup vs baseline: 1.0455x; 1.0455x over previous
//
#include <hip/hip_runtime.h>

#define RES 1024
#define NROOMS 8
#define NBUCKETS 256                 // 4 grid rows per bucket
#define BINS_PER_BUCKET (4 * RES)    // 4096 bins
#define CAP 32768                    // entries per bucket (mean ~19531, sigma ~140)
#define SWPB 8                       // waves per scatter block (512 threads)
#define AGB 8192                     // agents per block (512 thr * 16 agents)

typedef unsigned int u32x4 __attribute__((ext_vector_type(4)));

// ---------------------------------------------------------------------------
// Pass 1: partition agents into per-bucket segments of 2-byte bin codes.
// Packed per-agent state: (bucket<<24)|(elem<<12)|rank in ONE uint (rank<1024,
// elem<4096), validity in a 16-bit mask. NO launch_bounds wave cap (round 6's
// forced 85-VGPR cap serialized/spilled Phase A) and NO nontemporal loads.
// ---------------------------------------------------------------------------
__global__ __launch_bounds__(512) void scatter_kernel(
    const float4* __restrict__ pos, int n4, int nagents,
    unsigned short* __restrict__ buf, unsigned int* __restrict__ cursor)
{
    __shared__ unsigned int   cnt[SWPB][NBUCKETS];   // per-wave counts (rank src)
    __shared__ unsigned int   sbase[SWPB][NBUCKETS]; // staged base per (wave,bucket)
    __shared__ unsigned int   pstart[NBUCKETS];      // staged start per bucket
    __shared__ unsigned int   ptotal[NBUCKETS];      // block total per bucket
    __shared__ unsigned int   gbase[NBUCKETS];       // global base per bucket
    __shared__ unsigned int   wsum[4];
    __shared__ unsigned short staged[AGB];           // 16 KB

    int tid  = threadIdx.x;
    int wv   = tid >> 6;
    int lane = tid & 63;

    #pragma unroll
    for (int i = 0; i < (SWPB * NBUCKETS) / 512; ++i)
        ((unsigned int*)cnt)[tid + 512 * i] = 0u;
    __syncthreads();

    // Phase A: load agents, compute codes, count+rank in one LDS atomic.
    unsigned int pk[16];
    unsigned int valid = 0u;
    int base4 = blockIdx.x * (AGB / 2);              // 4096 float4 per block
    #pragma unroll
    for (int k = 0; k < 8; ++k) {
        int i4 = base4 + (k << 9) + tid;
        if (i4 < n4) {
            float4 p = pos[i4];
            int ix0 = min(max((int)(p.x * 1024.0f), 0), 1023);
            int iy0 = min(max((int)(p.y * 1024.0f), 0), 1023);
            int ix1 = min(max((int)(p.z * 1024.0f), 0), 1023);
            int iy1 = min(max((int)(p.w * 1024.0f), 0), 1023);
            unsigned int b0 = (unsigned int)(ix0 >> 2);
            unsigned int b1 = (unsigned int)(ix1 >> 2);
            unsigned int e0 = (unsigned int)(((ix0 & 3) << 10) | iy0);
            unsigned int e1 = (unsigned int)(((ix1 & 3) << 10) | iy1);
            unsigned int r0 = atomicAdd(&cnt[wv][b0], 1u);
            unsigned int r1 = atomicAdd(&cnt[wv][b1], 1u);
            pk[2 * k]     = (b0 << 24) | (e0 << 12) | (r0 & 0xFFFu);
            pk[2 * k + 1] = (b1 << 24) | (e1 << 12) | (r1 & 0xFFFu);
            valid |= 3u << (2 * k);
        }
    }
    __syncthreads();

    // Phase B: per-bucket totals, cross-wave bases, block prefix, reservation.
    if (tid < NBUCKETS) {
        unsigned int run = 0;
        #pragma unroll
        for (int w = 0; w < SWPB; ++w) {
            unsigned int c = cnt[w][tid];
            sbase[w][tid] = run;                     // wave-exclusive base
            run += c;
        }
        ptotal[tid] = run;
        gbase[tid]  = run ? atomicAdd(&cursor[tid], run) : 0u;
        unsigned int t = run;                        // inclusive scan within wave
        #pragma unroll
        for (int off = 1; off < 64; off <<= 1) {
            unsigned int v = (unsigned int)__shfl_up((int)t, off, 64);
            if (lane >= off) t += v;
        }
        if (lane == 63) wsum[wv] = t;
        pstart[tid] = t - run;                       // wave-local exclusive
    }
    __syncthreads();
    if (tid < NBUCKETS) {
        unsigned int off = 0;
        #pragma unroll
        for (int w = 0; w < 3; ++w) if (w < wv) off += wsum[w];
        unsigned int ps = pstart[tid] + off;         // block-local exclusive prefix
        pstart[tid] = ps;
        #pragma unroll
        for (int w = 0; w < SWPB; ++w) sbase[w][tid] += ps;
    }
    __syncthreads();

    // Phase C: scatter codes into LDS staging ordered by bucket.
    #pragma unroll
    for (int k = 0; k < 16; ++k) {
        if (valid & (1u << k)) {
            unsigned int cd = pk[k];
            unsigned int b = cd >> 24;
            staged[sbase[wv][b] + (cd & 0xFFFu)] =
                (unsigned short)((cd >> 12) & 0xFFFu);
        }
    }
    __syncthreads();

    // Phase D: coalesced copy-out; wave w owns buckets [32w, 32w+32).
    // Pair-packed uint stores with head/tail fixup for alignment.
    for (int bb = 0; bb < 32; ++bb) {
        int b = (wv << 5) + bb;
        unsigned int n = ptotal[b];
        if (n == 0) continue;
        unsigned int ps = pstart[b];
        unsigned int gb = gbase[b];
        unsigned int head = gb & 1u;                 // 1 -> first elem solo
        if (head && lane == 0) {
            if (gb < CAP) buf[b * CAP + gb] = staged[ps];
        }
        unsigned int body  = n - head;
        unsigned int npair = body >> 1;
        for (unsigned int q = lane; q < npair; q += 64) {
            unsigned int e  = head + 2 * q;
            unsigned int lo = staged[ps + e];
            unsigned int hi = staged[ps + e + 1];
            unsigned int p  = gb + e;                // even
            if (p + 1 < CAP)
                *(unsigned int*)(buf + (size_t)b * CAP + p) = lo | (hi << 16);
            else if (p < CAP)
                buf[(size_t)b * CAP + p] = (unsigned short)lo;
        }
        if ((body & 1u) && lane == 0) {
            unsigned int e = head + 2 * npair;
            unsigned int p = gb + e;
            if (p < CAP) buf[(size_t)b * CAP + p] = staged[ps + e];
        }
    }

    // odd-count tail agent
    if (blockIdx.x == 0 && tid == 0 && (nagents & 1)) {
        const float* t = (const float*)pos;
        float px = t[2 * (nagents - 1)];
        float py = t[2 * (nagents - 1) + 1];
        int ix = min(max((int)(px * 1024.0f), 0), 1023);
        int iy = min(max((int)(py * 1024.0f), 0), 1023);
        unsigned int b = (unsigned int)(ix >> 2);
        unsigned int p = atomicAdd(&cursor[b], 1u);
        if (p < CAP) buf[b * CAP + p] = (unsigned short)(((ix & 3) << 10) | iy);
    }
}

// ---------------------------------------------------------------------------
// Pass 2: one block per bucket — LDS histogram from paired-code reads,
// uint4 stores, fused block-max + one atomicMax. No pre-zero of counts.
// ---------------------------------------------------------------------------
__global__ __launch_bounds__(1024) void hist_build_kernel(
    const unsigned short* __restrict__ buf,
    const unsigned int* __restrict__ cursor,
    unsigned int* __restrict__ counts,
    unsigned int* __restrict__ out_max)
{
    __shared__ __align__(16) unsigned int h[BINS_PER_BUCKET];   // 16 KB
    int b = blockIdx.x, tid = threadIdx.x;
    #pragma unroll
    for (int i = 0; i < BINS_PER_BUCKET / 1024; ++i) h[tid + 1024 * i] = 0u;
    __syncthreads();

    unsigned int n = min(cursor[b], (unsigned int)CAP);
    const unsigned short* seg = buf + (size_t)b * CAP;
    unsigned int n2 = n & ~1u;
    for (unsigned int i = 2 * tid; i < n2; i += 2048) {
        unsigned int u = *(const unsigned int*)(seg + i);   // seg 4B-aligned, i even
        atomicAdd(&h[u & 0xFFFFu], 1u);
        atomicAdd(&h[u >> 16], 1u);
    }
    if (tid == 0 && (n & 1)) atomicAdd(&h[seg[n - 1]], 1u);
    __syncthreads();

    u32x4 v = ((const u32x4*)h)[tid];
    ((u32x4*)counts)[(size_t)b * (BINS_PER_BUCKET / 4) + tid] = v;
    unsigned int m = max(max(v.x, v.y), max(v.z, v.w));
    #pragma unroll
    for (int off = 32; off > 0; off >>= 1)
        m = max(m, (unsigned int)__shfl_down((int)m, off, 64));
    __shared__ unsigned int sm[16];
    if ((tid & 63) == 0) sm[tid >> 6] = m;
    __syncthreads();
    if (tid == 0) {
        #pragma unroll
        for (int w = 1; w < 16; ++w) m = max(m, sm[w]);
        atomicMax(out_max, m);
    }
}

// ---------------------------------------------------------------------------
// Fallback (direct global atomics) if ws_size is too small.
// ---------------------------------------------------------------------------
__global__ __launch_bounds__(256) void hist_atomic_kernel(
    const float4* __restrict__ pos, int n4, int nagents,
    unsigned int* __restrict__ counts)
{
    int idx = blockIdx.x * blockDim.x + threadIdx.x;
    int stride = gridDim.x * blockDim.x;
    for (int i = idx; i < n4; i += stride) {
        float4 p = pos[i];
        int ix0 = min(max((int)(p.x * 1024.0f), 0), 1023);
        int iy0 = min(max((int)(p.y * 1024.0f), 0), 1023);
        int ix1 = min(max((int)(p.z * 1024.0f), 0), 1023);
        int iy1 = min(max((int)(p.w * 1024.0f), 0), 1023);
        atomicAdd(&counts[(ix0 << 10) + iy0], 1u);
        atomicAdd(&counts[(ix1 << 10) + iy1], 1u);
    }
    if (idx == 0 && (nagents & 1)) {
        const float* t = (const float*)pos;
        int ix = min(max((int)(t[2 * (nagents - 1)] * 1024.0f), 0), 1023);
        int iy = min(max((int)(t[2 * (nagents - 1) + 1] * 1024.0f), 0), 1023);
        atomicAdd(&counts[(ix << 10) + iy], 1u);
    }
}

__global__ __launch_bounds__(256) void max_kernel(
    const uint4* __restrict__ counts, unsigned int* __restrict__ out_max)
{
    int idx = blockIdx.x * blockDim.x + threadIdx.x;
    int stride = gridDim.x * blockDim.x;
    unsigned int m = 0;
    const int n4 = (RES * RES) / 4;
    for (int i = idx; i < n4; i += stride) {
        uint4 c = counts[i];
        m = max(m, max(max(c.x, c.y), max(c.z, c.w)));
    }
    #pragma unroll
    for (int off = 32; off > 0; off >>= 1)
        m = max(m, (unsigned int)__shfl_down((int)m, off, 64));
    __shared__ unsigned int sm[4];
    if ((threadIdx.x & 63) == 0) sm[threadIdx.x >> 6] = m;
    __syncthreads();
    if (threadIdx.x == 0) {
        m = max(max(sm[0], sm[1]), max(sm[2], sm[3]));
        atomicMax(out_max, m);
    }
}

// ---------------------------------------------------------------------------
// Pass 3: dynamic_layout for 8 rooms + in-place flow normalization.
// (round-4 proven form: plain float4 loads/stores, no NT hints)
// ---------------------------------------------------------------------------
__global__ __launch_bounds__(256) void final_kernel(
    const float* __restrict__ room_params,
    const float4* __restrict__ wall,
    float4* __restrict__ dyn,
    float* __restrict__ flow,
    const unsigned int* __restrict__ maxp)
{
    int idx = blockIdx.x * blockDim.x + threadIdx.x;   // 0 .. 262143
    int i  = idx >> 8;
    int j0 = (idx & 255) << 2;

    const float inv1023 = 1.0f / 1023.0f;
    float x  = (float)i * inv1023;
    float y0 = (float)(j0 + 0) * inv1023;
    float y1 = (float)(j0 + 1) * inv1023;
    float y2 = (float)(j0 + 2) * inv1023;
    float y3 = (float)(j0 + 3) * inv1023;

    float4 w = wall[idx];
    float omx = 1.0f - w.x;
    float omy = 1.0f - w.y;
    float omz = 1.0f - w.z;
    float omw = 1.0f - w.w;

    uint4 c = ((const uint4*)flow)[idx];
    float inv = 1.0f / ((float)(*maxp) + 1e-6f);
    ((float4*)flow)[idx] = make_float4((float)c.x * inv, (float)c.y * inv,
                                       (float)c.z * inv, (float)c.w * inv);

    const int plane4 = (RES * RES) / 4;
    #pragma unroll
    for (int r = 0; r < NROOMS; ++r) {
        float cx = room_params[4 * r + 0];
        float cy = room_params[4 * r + 1];
        float sx = room_params[4 * r + 2];
        float sy = room_params[4 * r + 3];
        float isx = 1.0f / (2.0f * sx * sx);
        float isy = 1.0f / (2.0f * sy * sy);
        float dx = x - cx;
        float ax = dx * dx * isx;
        float d0 = y0 - cy, d1 = y1 - cy, d2 = y2 - cy, d3 = y3 - cy;
        float4 d;
        d.x = __expf(-(ax + d0 * d0 * isy)) * omx;
        d.y = __expf(-(ax + d1 * d1 * isy)) * omy;
        d.z = __expf(-(ax + d2 * d2 * isy)) * omz;
        d.w = __expf(-(ax + d3 * d3 * isy)) * omw;
        dyn[(size_t)r * plane4 + idx] = d;
    }
}

extern "C" void kernel_launch(void* const* d_in, const int* in_sizes, int n_in,
                              void* d_out, int out_size, void* d_ws, size_t ws_size,
                              hipStream_t stream) {
    const float* agents      = (const float*)d_in[0];  // (N,2)
    const float* room_params = (const float*)d_in[1];  // (8,4)
    const float* wall        = (const float*)d_in[2];  // (1024,1024)

    float* dyn  = (float*)d_out;
    float* flow = (float*)d_out + (size_t)NROOMS * RES * RES;
    unsigned int* counts = (unsigned int*)flow;

    int nagents = in_sizes[0] / 2;
    int n4 = nagents / 2;

    // ws layout: [0,1024) cursors, [1024,1028) max, [2048, 2048+16MB) buf
    size_t need = 2048 + (size_t)NBUCKETS * CAP * sizeof(unsigned short);

    if (ws_size >= need) {
        unsigned int*   cursor = (unsigned int*)d_ws;
        unsigned int*   maxp   = (unsigned int*)((char*)d_ws + 1024);
        unsigned short* buf    = (unsigned short*)((char*)d_ws + 2048);

        (void)hipMemsetAsync(d_ws, 0, 2048, stream);           // cursors + max
        int nblk = (n4 + (AGB / 2) - 1) / (AGB / 2);           // 4096 float4/block
        scatter_kernel<<<nblk, 512, 0, stream>>>((const float4*)agents, n4, nagents,
                                                 buf, cursor);
        hist_build_kernel<<<NBUCKETS, 1024, 0, stream>>>(buf, cursor, counts, maxp);
        final_kernel<<<(RES * RES / 4) / 256, 256, 0, stream>>>(
            room_params, (const float4*)wall, (float4*)dyn, flow, maxp);
    } else {
        unsigned int* maxp = (unsigned int*)d_ws;
        (void)hipMemsetAsync(flow, 0, (size_t)RES * RES * sizeof(float), stream);
        (void)hipMemsetAsync(maxp, 0, sizeof(unsigned int), stream);
        hist_atomic_kernel<<<1280, 256, 0, stream>>>((const float4*)agents, n4, nagents, counts);
        max_kernel<<<256, 256, 0, stream>>>((const uint4*)counts, maxp);
        final_kernel<<<(RES * RES / 4) / 256, 256, 0, stream>>>(
            room_params, (const float4*)wall, (float4*)dyn, flow, maxp);
    }
}

// Round 8
// 120.517 us; speedup vs baseline: 1.1248x; 1.0758x over previous
//
#include <hip/hip_runtime.h>

#define RES 1024
#define NROOMS 8
#define NBUCKETS 256                 // 4 grid rows per bucket
#define BINS_PER_BUCKET (4 * RES)    // 4096 bins
#define CAP 32768                    // entries per bucket (mean ~19531, sigma ~140)
#define SWPB 8                       // waves per scatter block (512 threads)
#define AGB 8192                     // agents per block (512 thr * 16 agents)

typedef unsigned int u32x4 __attribute__((ext_vector_type(4)));

// ---------------------------------------------------------------------------
// Device helper: compute one grid cell (4 columns) of all 8 dyn planes.
// ---------------------------------------------------------------------------
__device__ __forceinline__ void dyn_cell(
    const float* __restrict__ room_params,
    const float4* __restrict__ wall,
    float4* __restrict__ dyn, int idx)
{
    int i  = idx >> 8;
    int j0 = (idx & 255) << 2;
    const float inv1023 = 1.0f / 1023.0f;
    float x  = (float)i * inv1023;
    float y0 = (float)(j0 + 0) * inv1023;
    float y1 = (float)(j0 + 1) * inv1023;
    float y2 = (float)(j0 + 2) * inv1023;
    float y3 = (float)(j0 + 3) * inv1023;

    float4 w = wall[idx];
    float omx = 1.0f - w.x;
    float omy = 1.0f - w.y;
    float omz = 1.0f - w.z;
    float omw = 1.0f - w.w;

    const int plane4 = (RES * RES) / 4;
    #pragma unroll
    for (int r = 0; r < NROOMS; ++r) {
        float cx = room_params[4 * r + 0];
        float cy = room_params[4 * r + 1];
        float sx = room_params[4 * r + 2];
        float sy = room_params[4 * r + 3];
        float isx = 1.0f / (2.0f * sx * sx);
        float isy = 1.0f / (2.0f * sy * sy);
        float dx = x - cx;
        float ax = dx * dx * isx;
        float d0 = y0 - cy, d1 = y1 - cy, d2 = y2 - cy, d3 = y3 - cy;
        float4 d;
        d.x = __expf(-(ax + d0 * d0 * isy)) * omx;
        d.y = __expf(-(ax + d1 * d1 * isy)) * omy;
        d.z = __expf(-(ax + d2 * d2 * isy)) * omz;
        d.w = __expf(-(ax + d3 * d3 * isy)) * omw;
        dyn[(size_t)r * plane4 + idx] = d;
    }
}

// ---------------------------------------------------------------------------
// Pass 1: partition agents into per-bucket segments of 2-byte bin codes
// (round-4 proven form), PLUS fused dyn-plane computation in the tail —
// scatter is latency-bound (HBM ~10%, VALU ~7%), so the 36 MB of dyn
// stores ride the idle memory pipe. Placed after Phase D so code[]/rank[]
// are dead (no extra register pressure).
// ---------------------------------------------------------------------------
__global__ __launch_bounds__(512) void scatter_kernel(
    const float4* __restrict__ pos, int n4, int nagents,
    unsigned short* __restrict__ buf, unsigned int* __restrict__ cursor,
    const float* __restrict__ room_params,
    const float4* __restrict__ wall,
    float4* __restrict__ dyn)
{
    __shared__ unsigned int   cnt[SWPB][NBUCKETS];   // count, then reused as rank
    __shared__ unsigned int   sbase[SWPB][NBUCKETS]; // staged base per (wave,bucket)
    __shared__ unsigned int   pstart[NBUCKETS];      // staged start per bucket
    __shared__ unsigned int   ptotal[NBUCKETS];      // block total per bucket
    __shared__ unsigned int   gbase[NBUCKETS];       // global base per bucket
    __shared__ unsigned int   wsum[4];
    __shared__ unsigned short staged[AGB];           // 16 KB

    int tid  = threadIdx.x;
    int wv   = tid >> 6;
    int lane = tid & 63;

    #pragma unroll
    for (int i = 0; i < (SWPB * NBUCKETS) / 512; ++i)
        ((unsigned int*)cnt)[tid + 512 * i] = 0u;
    __syncthreads();

    // Phase A: load agents, compute codes, count+rank in one LDS atomic.
    unsigned int   code[16];         // (bucket<<16) | local_bin; 0xFFFFFFFF invalid
    unsigned short rank[16];
    int base4 = blockIdx.x * (AGB / 2);              // 4096 float4 per block
    #pragma unroll
    for (int k = 0; k < 8; ++k) {
        int i4 = base4 + (k << 9) + tid;
        if (i4 < n4) {
            float4 p = pos[i4];
            int ix0 = min(max((int)(p.x * 1024.0f), 0), 1023);
            int iy0 = min(max((int)(p.y * 1024.0f), 0), 1023);
            int ix1 = min(max((int)(p.z * 1024.0f), 0), 1023);
            int iy1 = min(max((int)(p.w * 1024.0f), 0), 1023);
            unsigned int b0 = (unsigned int)(ix0 >> 2);
            unsigned int b1 = (unsigned int)(ix1 >> 2);
            code[2 * k]     = (b0 << 16) | (unsigned int)(((ix0 & 3) << 10) | iy0);
            code[2 * k + 1] = (b1 << 16) | (unsigned int)(((ix1 & 3) << 10) | iy1);
            rank[2 * k]     = (unsigned short)atomicAdd(&cnt[wv][b0], 1u);
            rank[2 * k + 1] = (unsigned short)atomicAdd(&cnt[wv][b1], 1u);
        } else {
            code[2 * k] = 0xFFFFFFFFu;
            code[2 * k + 1] = 0xFFFFFFFFu;
        }
    }
    __syncthreads();

    // Phase B: per-bucket totals, cross-wave bases, block prefix, reservation.
    if (tid < NBUCKETS) {
        unsigned int run = 0;
        #pragma unroll
        for (int w = 0; w < SWPB; ++w) {
            unsigned int c = cnt[w][tid];
            sbase[w][tid] = run;                     // wave-exclusive base
            run += c;
        }
        ptotal[tid] = run;
        gbase[tid]  = run ? atomicAdd(&cursor[tid], run) : 0u;
        unsigned int t = run;                        // inclusive scan within wave
        #pragma unroll
        for (int off = 1; off < 64; off <<= 1) {
            unsigned int v = (unsigned int)__shfl_up((int)t, off, 64);
            if (lane >= off) t += v;
        }
        if (lane == 63) wsum[wv] = t;
        pstart[tid] = t - run;                       // wave-local exclusive
    }
    __syncthreads();
    if (tid < NBUCKETS) {
        unsigned int off = 0;
        #pragma unroll
        for (int w = 0; w < 3; ++w) if (w < wv) off += wsum[w];
        unsigned int ps = pstart[tid] + off;         // block-local exclusive prefix
        pstart[tid] = ps;
        #pragma unroll
        for (int w = 0; w < SWPB; ++w) sbase[w][tid] += ps;
    }
    __syncthreads();

    // Phase C: scatter codes into LDS staging ordered by bucket.
    #pragma unroll
    for (int k = 0; k < 16; ++k) {
        unsigned int cd = code[k];
        if (cd != 0xFFFFFFFFu) {
            unsigned int b = cd >> 16;
            staged[sbase[wv][b] + rank[k]] = (unsigned short)(cd & 0xFFFFu);
        }
    }
    __syncthreads();

    // Phase D: coalesced copy-out; wave w owns buckets [32w, 32w+32).
    #pragma unroll 4
    for (int bb = 0; bb < 32; ++bb) {
        int b = (wv << 5) + bb;
        unsigned int n  = ptotal[b];
        unsigned int ps = pstart[b];
        unsigned int gb = gbase[b];
        for (unsigned int e = lane; e < n; e += 64) {
            unsigned int p = gb + e;
            if (p < CAP) buf[b * CAP + p] = staged[ps + e];
        }
    }

    // Fused dyn-plane computation (independent of histogram).
    int gid = blockIdx.x * 512 + tid;
    if (gid < (RES * RES) / 4)
        dyn_cell(room_params, wall, dyn, gid);

    // odd-count tail agent
    if (blockIdx.x == 0 && tid == 0 && (nagents & 1)) {
        const float* t = (const float*)pos;
        float px = t[2 * (nagents - 1)];
        float py = t[2 * (nagents - 1) + 1];
        int ix = min(max((int)(px * 1024.0f), 0), 1023);
        int iy = min(max((int)(py * 1024.0f), 0), 1023);
        unsigned int b = (unsigned int)(ix >> 2);
        unsigned int p = atomicAdd(&cursor[b], 1u);
        if (p < CAP) buf[b * CAP + p] = (unsigned short)(((ix & 3) << 10) | iy);
    }
}

// ---------------------------------------------------------------------------
// Pass 2: one block per bucket — LDS histogram from paired-code reads,
// uint4 stores, fused block-max + one atomicMax. No pre-zero of counts.
// ---------------------------------------------------------------------------
__global__ __launch_bounds__(1024) void hist_build_kernel(
    const unsigned short* __restrict__ buf,
    const unsigned int* __restrict__ cursor,
    unsigned int* __restrict__ counts,
    unsigned int* __restrict__ out_max)
{
    __shared__ __align__(16) unsigned int h[BINS_PER_BUCKET];   // 16 KB
    int b = blockIdx.x, tid = threadIdx.x;
    #pragma unroll
    for (int i = 0; i < BINS_PER_BUCKET / 1024; ++i) h[tid + 1024 * i] = 0u;
    __syncthreads();

    unsigned int n = min(cursor[b], (unsigned int)CAP);
    const unsigned short* seg = buf + (size_t)b * CAP;
    unsigned int n2 = n & ~1u;
    for (unsigned int i = 2 * tid; i < n2; i += 2048) {
        unsigned int u = *(const unsigned int*)(seg + i);   // seg 4B-aligned, i even
        atomicAdd(&h[u & 0xFFFFu], 1u);
        atomicAdd(&h[u >> 16], 1u);
    }
    if (tid == 0 && (n & 1)) atomicAdd(&h[seg[n - 1]], 1u);
    __syncthreads();

    u32x4 v = ((const u32x4*)h)[tid];
    ((u32x4*)counts)[(size_t)b * (BINS_PER_BUCKET / 4) + tid] = v;
    unsigned int m = max(max(v.x, v.y), max(v.z, v.w));
    #pragma unroll
    for (int off = 32; off > 0; off >>= 1)
        m = max(m, (unsigned int)__shfl_down((int)m, off, 64));
    __shared__ unsigned int sm[16];
    if ((tid & 63) == 0) sm[tid >> 6] = m;
    __syncthreads();
    if (tid == 0) {
        #pragma unroll
        for (int w = 1; w < 16; ++w) m = max(m, sm[w]);
        atomicMax(out_max, m);
    }
}

// ---------------------------------------------------------------------------
// Pass 3 (main path): normalize flow counts in place. Counts are L2-warm.
// ---------------------------------------------------------------------------
__global__ __launch_bounds__(256) void norm_kernel(
    float* __restrict__ flow, const unsigned int* __restrict__ maxp)
{
    int idx = blockIdx.x * blockDim.x + threadIdx.x;   // 0 .. 65535
    uint4 c = ((const uint4*)flow)[idx];
    float inv = 1.0f / ((float)(*maxp) + 1e-6f);
    ((float4*)flow)[idx] = make_float4((float)c.x * inv, (float)c.y * inv,
                                       (float)c.z * inv, (float)c.w * inv);
}

// ---------------------------------------------------------------------------
// Fallback path (ws too small): direct global atomics + max + full final.
// ---------------------------------------------------------------------------
__global__ __launch_bounds__(256) void hist_atomic_kernel(
    const float4* __restrict__ pos, int n4, int nagents,
    unsigned int* __restrict__ counts)
{
    int idx = blockIdx.x * blockDim.x + threadIdx.x;
    int stride = gridDim.x * blockDim.x;
    for (int i = idx; i < n4; i += stride) {
        float4 p = pos[i];
        int ix0 = min(max((int)(p.x * 1024.0f), 0), 1023);
        int iy0 = min(max((int)(p.y * 1024.0f), 0), 1023);
        int ix1 = min(max((int)(p.z * 1024.0f), 0), 1023);
        int iy1 = min(max((int)(p.w * 1024.0f), 0), 1023);
        atomicAdd(&counts[(ix0 << 10) + iy0], 1u);
        atomicAdd(&counts[(ix1 << 10) + iy1], 1u);
    }
    if (idx == 0 && (nagents & 1)) {
        const float* t = (const float*)pos;
        int ix = min(max((int)(t[2 * (nagents - 1)] * 1024.0f), 0), 1023);
        int iy = min(max((int)(t[2 * (nagents - 1) + 1] * 1024.0f), 0), 1023);
        atomicAdd(&counts[(ix << 10) + iy], 1u);
    }
}

__global__ __launch_bounds__(256) void max_kernel(
    const uint4* __restrict__ counts, unsigned int* __restrict__ out_max)
{
    int idx = blockIdx.x * blockDim.x + threadIdx.x;
    int stride = gridDim.x * blockDim.x;
    unsigned int m = 0;
    const int n4 = (RES * RES) / 4;
    for (int i = idx; i < n4; i += stride) {
        uint4 c = counts[i];
        m = max(m, max(max(c.x, c.y), max(c.z, c.w)));
    }
    #pragma unroll
    for (int off = 32; off > 0; off >>= 1)
        m = max(m, (unsigned int)__shfl_down((int)m, off, 64));
    __shared__ unsigned int sm[4];
    if ((threadIdx.x & 63) == 0) sm[threadIdx.x >> 6] = m;
    __syncthreads();
    if (threadIdx.x == 0) {
        m = max(max(sm[0], sm[1]), max(sm[2], sm[3]));
        atomicMax(out_max, m);
    }
}

__global__ __launch_bounds__(256) void final_full_kernel(
    const float* __restrict__ room_params,
    const float4* __restrict__ wall,
    float4* __restrict__ dyn,
    float* __restrict__ flow,
    const unsigned int* __restrict__ maxp)
{
    int idx = blockIdx.x * blockDim.x + threadIdx.x;   // 0 .. 262143
    uint4 c = ((const uint4*)flow)[idx];
    float inv = 1.0f / ((float)(*maxp) + 1e-6f);
    ((float4*)flow)[idx] = make_float4((float)c.x * inv, (float)c.y * inv,
                                       (float)c.z * inv, (float)c.w * inv);
    dyn_cell(room_params, wall, dyn, idx);
}

extern "C" void kernel_launch(void* const* d_in, const int* in_sizes, int n_in,
                              void* d_out, int out_size, void* d_ws, size_t ws_size,
                              hipStream_t stream) {
    const float* agents      = (const float*)d_in[0];  // (N,2)
    const float* room_params = (const float*)d_in[1];  // (8,4)
    const float* wall        = (const float*)d_in[2];  // (1024,1024)

    float* dyn  = (float*)d_out;
    float* flow = (float*)d_out + (size_t)NROOMS * RES * RES;
    unsigned int* counts = (unsigned int*)flow;

    int nagents = in_sizes[0] / 2;
    int n4 = nagents / 2;

    // ws layout: [0,1024) cursors, [1024,1028) max, [2048, 2048+16MB) buf
    size_t need = 2048 + (size_t)NBUCKETS * CAP * sizeof(unsigned short);

    if (ws_size >= need) {
        unsigned int*   cursor = (unsigned int*)d_ws;
        unsigned int*   maxp   = (unsigned int*)((char*)d_ws + 1024);
        unsigned short* buf    = (unsigned short*)((char*)d_ws + 2048);

        (void)hipMemsetAsync(d_ws, 0, 2048, stream);           // cursors + max
        int nblk = (n4 + (AGB / 2) - 1) / (AGB / 2);           // 4096 float4/block
        scatter_kernel<<<nblk, 512, 0, stream>>>(
            (const float4*)agents, n4, nagents, buf, cursor,
            room_params, (const float4*)wall, (float4*)dyn);
        hist_build_kernel<<<NBUCKETS, 1024, 0, stream>>>(buf, cursor, counts, maxp);
        norm_kernel<<<(RES * RES / 4) / 256, 256, 0, stream>>>(flow, maxp);
    } else {
        unsigned int* maxp = (unsigned int*)d_ws;
        (void)hipMemsetAsync(flow, 0, (size_t)RES * RES * sizeof(float), stream);
        (void)hipMemsetAsync(maxp, 0, sizeof(unsigned int), stream);
        hist_atomic_kernel<<<1280, 256, 0, stream>>>((const float4*)agents, n4, nagents, counts);
        max_kernel<<<256, 256, 0, stream>>>((const uint4*)counts, maxp);
        final_full_kernel<<<(RES * RES / 4) / 256, 256, 0, stream>>>(
            room_params, (const float4*)wall, (float4*)dyn, flow, maxp);
    }
}

// Round 9
// 119.808 us; speedup vs baseline: 1.1314x; 1.0059x over previous
//
#include <hip/hip_runtime.h>

#define RES 1024
#define NROOMS 8
#define NBUCKETS 256                 // 4 grid rows per bucket
#define BINS_PER_BUCKET (4 * RES)    // 4096 bins
#define CAP 32768                    // entries per bucket (mean ~19531, sigma ~140)
#define SWPB 8                       // waves per scatter block (512 threads)
#define NBLK 512                     // exactly 2 blocks/CU -> no tail quantization
#define F4PT 10                      // max float4 per thread (ceil(2.5M/512/512))
#define AGB_MAX (NBLK * 2 * F4PT)    // not used for sizing LDS directly
#define STG_MAX (512 * F4PT * 2)     // max agents staged per block (10240)

typedef unsigned int u32x4 __attribute__((ext_vector_type(4)));

// ---------------------------------------------------------------------------
// Device helper: compute one grid cell (4 columns) of all 8 dyn planes.
// ---------------------------------------------------------------------------
__device__ __forceinline__ void dyn_cell(
    const float* __restrict__ room_params,
    const float4* __restrict__ wall,
    float4* __restrict__ dyn, int idx)
{
    int i  = idx >> 8;
    int j0 = (idx & 255) << 2;
    const float inv1023 = 1.0f / 1023.0f;
    float x  = (float)i * inv1023;
    float y0 = (float)(j0 + 0) * inv1023;
    float y1 = (float)(j0 + 1) * inv1023;
    float y2 = (float)(j0 + 2) * inv1023;
    float y3 = (float)(j0 + 3) * inv1023;

    float4 w = wall[idx];
    float omx = 1.0f - w.x;
    float omy = 1.0f - w.y;
    float omz = 1.0f - w.z;
    float omw = 1.0f - w.w;

    const int plane4 = (RES * RES) / 4;
    #pragma unroll
    for (int r = 0; r < NROOMS; ++r) {
        float cx = room_params[4 * r + 0];
        float cy = room_params[4 * r + 1];
        float sx = room_params[4 * r + 2];
        float sy = room_params[4 * r + 3];
        float isx = 1.0f / (2.0f * sx * sx);
        float isy = 1.0f / (2.0f * sy * sy);
        float dx = x - cx;
        float ax = dx * dx * isx;
        float d0 = y0 - cy, d1 = y1 - cy, d2 = y2 - cy, d3 = y3 - cy;
        float4 d;
        d.x = __expf(-(ax + d0 * d0 * isy)) * omx;
        d.y = __expf(-(ax + d1 * d1 * isy)) * omy;
        d.z = __expf(-(ax + d2 * d2 * isy)) * omz;
        d.w = __expf(-(ax + d3 * d3 * isy)) * omw;
        dyn[(size_t)r * plane4 + idx] = d;
    }
}

// ---------------------------------------------------------------------------
// Pass 1: partition agents into per-bucket segments of 2-byte bin codes,
// fused with dyn-plane computation. Launched with EXACTLY 512 blocks
// (2/CU) — each block derives its agent range from blockIdx, eliminating
// the 611-block 3-wave tail (2.39 blocks/CU -> 39%-utilized third wave).
// ---------------------------------------------------------------------------
__global__ __launch_bounds__(512) void scatter_kernel(
    const float4* __restrict__ pos, int n4, int nagents,
    unsigned short* __restrict__ buf, unsigned int* __restrict__ cursor,
    const float* __restrict__ room_params,
    const float4* __restrict__ wall,
    float4* __restrict__ dyn)
{
    __shared__ unsigned int   cnt[SWPB][NBUCKETS];   // count, then rank source
    __shared__ unsigned int   sbase[SWPB][NBUCKETS]; // staged base per (wave,bucket)
    __shared__ unsigned int   pstart[NBUCKETS];      // staged start per bucket
    __shared__ unsigned int   ptotal[NBUCKETS];      // block total per bucket
    __shared__ unsigned int   gbase[NBUCKETS];       // global base per bucket
    __shared__ unsigned int   wsum[4];
    __shared__ unsigned short staged[STG_MAX];       // 20 KB

    int tid  = threadIdx.x;
    int wv   = tid >> 6;
    int lane = tid & 63;

    #pragma unroll
    for (int i = 0; i < (SWPB * NBUCKETS) / 512; ++i)
        ((unsigned int*)cnt)[tid + 512 * i] = 0u;
    __syncthreads();

    // Agent range for this block: chunk = ceil(n4 / NBLK) float4's.
    int chunk = (n4 + NBLK - 1) / NBLK;
    int start = blockIdx.x * chunk;
    int end   = min(start + chunk, n4);

    // Phase A: load agents, compute codes, count+rank in one LDS atomic.
    unsigned int   code[2 * F4PT];   // (bucket<<16)|local_bin; 0xFFFFFFFF invalid
    unsigned short rank[2 * F4PT];
    #pragma unroll
    for (int k = 0; k < F4PT; ++k) {
        int i4 = start + (k << 9) + tid;
        if (i4 < end) {
            float4 p = pos[i4];
            int ix0 = min(max((int)(p.x * 1024.0f), 0), 1023);
            int iy0 = min(max((int)(p.y * 1024.0f), 0), 1023);
            int ix1 = min(max((int)(p.z * 1024.0f), 0), 1023);
            int iy1 = min(max((int)(p.w * 1024.0f), 0), 1023);
            unsigned int b0 = (unsigned int)(ix0 >> 2);
            unsigned int b1 = (unsigned int)(ix1 >> 2);
            code[2 * k]     = (b0 << 16) | (unsigned int)(((ix0 & 3) << 10) | iy0);
            code[2 * k + 1] = (b1 << 16) | (unsigned int)(((ix1 & 3) << 10) | iy1);
            rank[2 * k]     = (unsigned short)atomicAdd(&cnt[wv][b0], 1u);
            rank[2 * k + 1] = (unsigned short)atomicAdd(&cnt[wv][b1], 1u);
        } else {
            code[2 * k] = 0xFFFFFFFFu;
            code[2 * k + 1] = 0xFFFFFFFFu;
        }
    }
    __syncthreads();

    // Phase B: per-bucket totals, cross-wave bases, block prefix, reservation.
    if (tid < NBUCKETS) {
        unsigned int run = 0;
        #pragma unroll
        for (int w = 0; w < SWPB; ++w) {
            unsigned int c = cnt[w][tid];
            sbase[w][tid] = run;                     // wave-exclusive base
            run += c;
        }
        ptotal[tid] = run;
        gbase[tid]  = run ? atomicAdd(&cursor[tid], run) : 0u;
        unsigned int t = run;                        // inclusive scan within wave
        #pragma unroll
        for (int off = 1; off < 64; off <<= 1) {
            unsigned int v = (unsigned int)__shfl_up((int)t, off, 64);
            if (lane >= off) t += v;
        }
        if (lane == 63) wsum[wv] = t;
        pstart[tid] = t - run;                       // wave-local exclusive
    }
    __syncthreads();
    if (tid < NBUCKETS) {
        unsigned int off = 0;
        #pragma unroll
        for (int w = 0; w < 3; ++w) if (w < wv) off += wsum[w];
        unsigned int ps = pstart[tid] + off;         // block-local exclusive prefix
        pstart[tid] = ps;
        #pragma unroll
        for (int w = 0; w < SWPB; ++w) sbase[w][tid] += ps;
    }
    __syncthreads();

    // Phase C: scatter codes into LDS staging ordered by bucket.
    #pragma unroll
    for (int k = 0; k < 2 * F4PT; ++k) {
        unsigned int cd = code[k];
        if (cd != 0xFFFFFFFFu) {
            unsigned int b = cd >> 16;
            staged[sbase[wv][b] + rank[k]] = (unsigned short)(cd & 0xFFFFu);
        }
    }
    __syncthreads();

    // Phase D: coalesced copy-out; wave w owns buckets [32w, 32w+32).
    #pragma unroll 4
    for (int bb = 0; bb < 32; ++bb) {
        int b = (wv << 5) + bb;
        unsigned int n  = ptotal[b];
        unsigned int ps = pstart[b];
        unsigned int gb = gbase[b];
        for (unsigned int e = lane; e < n; e += 64) {
            unsigned int p = gb + e;
            if (p < CAP) buf[b * CAP + p] = staged[ps + e];
        }
    }

    // Fused dyn-plane computation: 512 blocks * 512 thr == RES*RES/4 exactly.
    dyn_cell(room_params, wall, dyn, blockIdx.x * 512 + tid);

    // odd-count tail agent
    if (blockIdx.x == 0 && tid == 0 && (nagents & 1)) {
        const float* t = (const float*)pos;
        float px = t[2 * (nagents - 1)];
        float py = t[2 * (nagents - 1) + 1];
        int ix = min(max((int)(px * 1024.0f), 0), 1023);
        int iy = min(max((int)(py * 1024.0f), 0), 1023);
        unsigned int b = (unsigned int)(ix >> 2);
        unsigned int p = atomicAdd(&cursor[b], 1u);
        if (p < CAP) buf[b * CAP + p] = (unsigned short)(((ix & 3) << 10) | iy);
    }
}

// ---------------------------------------------------------------------------
// Pass 2: one block per bucket — LDS histogram from paired-code reads,
// uint4 stores, fused block-max + one atomicMax. No pre-zero of counts.
// ---------------------------------------------------------------------------
__global__ __launch_bounds__(1024) void hist_build_kernel(
    const unsigned short* __restrict__ buf,
    const unsigned int* __restrict__ cursor,
    unsigned int* __restrict__ counts,
    unsigned int* __restrict__ out_max)
{
    __shared__ __align__(16) unsigned int h[BINS_PER_BUCKET];   // 16 KB
    int b = blockIdx.x, tid = threadIdx.x;
    #pragma unroll
    for (int i = 0; i < BINS_PER_BUCKET / 1024; ++i) h[tid + 1024 * i] = 0u;
    __syncthreads();

    unsigned int n = min(cursor[b], (unsigned int)CAP);
    const unsigned short* seg = buf + (size_t)b * CAP;
    unsigned int n2 = n & ~1u;
    for (unsigned int i = 2 * tid; i < n2; i += 2048) {
        unsigned int u = *(const unsigned int*)(seg + i);   // seg 4B-aligned, i even
        atomicAdd(&h[u & 0xFFFFu], 1u);
        atomicAdd(&h[u >> 16], 1u);
    }
    if (tid == 0 && (n & 1)) atomicAdd(&h[seg[n - 1]], 1u);
    __syncthreads();

    u32x4 v = ((const u32x4*)h)[tid];
    ((u32x4*)counts)[(size_t)b * (BINS_PER_BUCKET / 4) + tid] = v;
    unsigned int m = max(max(v.x, v.y), max(v.z, v.w));
    #pragma unroll
    for (int off = 32; off > 0; off >>= 1)
        m = max(m, (unsigned int)__shfl_down((int)m, off, 64));
    __shared__ unsigned int sm[16];
    if ((tid & 63) == 0) sm[tid >> 6] = m;
    __syncthreads();
    if (tid == 0) {
        #pragma unroll
        for (int w = 1; w < 16; ++w) m = max(m, sm[w]);
        atomicMax(out_max, m);
    }
}

// ---------------------------------------------------------------------------
// Pass 3 (main path): normalize flow counts in place. Counts are L2-warm.
// ---------------------------------------------------------------------------
__global__ __launch_bounds__(256) void norm_kernel(
    float* __restrict__ flow, const unsigned int* __restrict__ maxp)
{
    int idx = blockIdx.x * blockDim.x + threadIdx.x;   // 0 .. 65535
    uint4 c = ((const uint4*)flow)[idx];
    float inv = 1.0f / ((float)(*maxp) + 1e-6f);
    ((float4*)flow)[idx] = make_float4((float)c.x * inv, (float)c.y * inv,
                                       (float)c.z * inv, (float)c.w * inv);
}

// ---------------------------------------------------------------------------
// Fallback path (ws too small): direct global atomics + max + full final.
// ---------------------------------------------------------------------------
__global__ __launch_bounds__(256) void hist_atomic_kernel(
    const float4* __restrict__ pos, int n4, int nagents,
    unsigned int* __restrict__ counts)
{
    int idx = blockIdx.x * blockDim.x + threadIdx.x;
    int stride = gridDim.x * blockDim.x;
    for (int i = idx; i < n4; i += stride) {
        float4 p = pos[i];
        int ix0 = min(max((int)(p.x * 1024.0f), 0), 1023);
        int iy0 = min(max((int)(p.y * 1024.0f), 0), 1023);
        int ix1 = min(max((int)(p.z * 1024.0f), 0), 1023);
        int iy1 = min(max((int)(p.w * 1024.0f), 0), 1023);
        atomicAdd(&counts[(ix0 << 10) + iy0], 1u);
        atomicAdd(&counts[(ix1 << 10) + iy1], 1u);
    }
    if (idx == 0 && (nagents & 1)) {
        const float* t = (const float*)pos;
        int ix = min(max((int)(t[2 * (nagents - 1)] * 1024.0f), 0), 1023);
        int iy = min(max((int)(t[2 * (nagents - 1) + 1] * 1024.0f), 0), 1023);
        atomicAdd(&counts[(ix << 10) + iy], 1u);
    }
}

__global__ __launch_bounds__(256) void max_kernel(
    const uint4* __restrict__ counts, unsigned int* __restrict__ out_max)
{
    int idx = blockIdx.x * blockDim.x + threadIdx.x;
    int stride = gridDim.x * blockDim.x;
    unsigned int m = 0;
    const int n4 = (RES * RES) / 4;
    for (int i = idx; i < n4; i += stride) {
        uint4 c = counts[i];
        m = max(m, max(max(c.x, c.y), max(c.z, c.w)));
    }
    #pragma unroll
    for (int off = 32; off > 0; off >>= 1)
        m = max(m, (unsigned int)__shfl_down((int)m, off, 64));
    __shared__ unsigned int sm[4];
    if ((threadIdx.x & 63) == 0) sm[threadIdx.x >> 6] = m;
    __syncthreads();
    if (threadIdx.x == 0) {
        m = max(max(sm[0], sm[1]), max(sm[2], sm[3]));
        atomicMax(out_max, m);
    }
}

__global__ __launch_bounds__(256) void final_full_kernel(
    const float* __restrict__ room_params,
    const float4* __restrict__ wall,
    float4* __restrict__ dyn,
    float* __restrict__ flow,
    const unsigned int* __restrict__ maxp)
{
    int idx = blockIdx.x * blockDim.x + threadIdx.x;   // 0 .. 262143
    uint4 c = ((const uint4*)flow)[idx];
    float inv = 1.0f / ((float)(*maxp) + 1e-6f);
    ((float4*)flow)[idx] = make_float4((float)c.x * inv, (float)c.y * inv,
                                       (float)c.z * inv, (float)c.w * inv);
    dyn_cell(room_params, wall, dyn, idx);
}

extern "C" void kernel_launch(void* const* d_in, const int* in_sizes, int n_in,
                              void* d_out, int out_size, void* d_ws, size_t ws_size,
                              hipStream_t stream) {
    const float* agents      = (const float*)d_in[0];  // (N,2)
    const float* room_params = (const float*)d_in[1];  // (8,4)
    const float* wall        = (const float*)d_in[2];  // (1024,1024)

    float* dyn  = (float*)d_out;
    float* flow = (float*)d_out + (size_t)NROOMS * RES * RES;
    unsigned int* counts = (unsigned int*)flow;

    int nagents = in_sizes[0] / 2;
    int n4 = nagents / 2;

    // ws layout: [0,1024) cursors, [1024,1028) max, [2048, 2048+16MB) buf
    size_t need = 2048 + (size_t)NBUCKETS * CAP * sizeof(unsigned short);

    // main path requires the per-block agent range to fit F4PT float4/thread
    bool fits = ((n4 + NBLK - 1) / NBLK) <= (F4PT * 512);

    if (ws_size >= need && fits) {
        unsigned int*   cursor = (unsigned int*)d_ws;
        unsigned int*   maxp   = (unsigned int*)((char*)d_ws + 1024);
        unsigned short* buf    = (unsigned short*)((char*)d_ws + 2048);

        (void)hipMemsetAsync(d_ws, 0, 2048, stream);           // cursors + max
        scatter_kernel<<<NBLK, 512, 0, stream>>>(
            (const float4*)agents, n4, nagents, buf, cursor,
            room_params, (const float4*)wall, (float4*)dyn);
        hist_build_kernel<<<NBUCKETS, 1024, 0, stream>>>(buf, cursor, counts, maxp);
        norm_kernel<<<(RES * RES / 4) / 256, 256, 0, stream>>>(flow, maxp);
    } else {
        unsigned int* maxp = (unsigned int*)d_ws;
        (void)hipMemsetAsync(flow, 0, (size_t)RES * RES * sizeof(float), stream);
        (void)hipMemsetAsync(maxp, 0, sizeof(unsigned int), stream);
        hist_atomic_kernel<<<1280, 256, 0, stream>>>((const float4*)agents, n4, nagents, counts);
        max_kernel<<<256, 256, 0, stream>>>((const uint4*)counts, maxp);
        final_full_kernel<<<(RES * RES / 4) / 256, 256, 0, stream>>>(
            room_params, (const float4*)wall, (float4*)dyn, flow, maxp);
    }
}